// Round 6
// baseline (885.263 us; speedup 1.0000x reference)
//
#include <hip/hip_runtime.h>
#include <stdint.h>

// ProgressiveVQ: 8-stage residual VQ, T=131072 rows, D=256, K=1024 codewords/stage.
// out[0:T*D] = recon ; out[T*D..+8] = per-stage MSE (= mean(residual_i^2)).
//
// R6: r=1 @ 3 waves/SIMD — the one feasible cell left in the {regs, LDS
// traffic, TLP} triangle (R1: r=2@2/SIMD latency-bound 40%; R2/R3/R4: reg
// wall; R5: global-direct slower than LDS).
//   * 4-wave (256-thr) blocks, 32 rows/wave (ONE m-tile): state ~125 regs
//     (af 64 + acc 16 + mv 16 + temps) vs 170 budget at 3 waves/SIMD.
//     __launch_bounds__(256,3); grid 1024 -> 3 blocks/CU resident (tail ~9%).
//   * LDS ~50KB: 3 x 16KB ring ONLY (cnorm read from global at chunk top,
//     consumed at pack). 3 blocks x 50KB = 150KB/CU.
//   * B-FRAGMENT global layout (R5): wsb[g][s][hi][c32], g = flat chunk
//     st*32+ch. Staging = linear copy (global_load_lds, no swizzle);
//     LDS read for MFMA B at step s = buf + s*1024 + lane*16 (fully linear,
//     conflict-free); the fragment stream is linear ACROSS stages so the
//     ring prefetch (gt=g+2, slot gt%3) crosses stage boundaries untouched.
//   * single barrier per chunk; counted vmcnt(4) (one chunk pair in flight);
//     prefetch issued at bottom; acc zero-init, -||c||^2/2 deferred to pack;
//     fmax-only argmax with index packed in low 10 mantissa bits.
//   * vq_prep rewritten WRITE-COALESCED for the B-frag layout (R5's prep
//     scattered 16B writes; that cost ~60us): phase 1 copies a contiguous
//     4KB span per block (reads transpose-scattered, writes linear), phase 2
//     computes cnorm with the old coalesced-read shfl reduction.
//   bf16-carried residual (argmin near-ties only; validated r4-r9,
//   absmax <=4.5e-3). ||r||^2 recursion gives MSE free.

#define T_ROWS   131072
#define DIM      256
#define NSTAGE   8
#define NCB      1024
#define WROWS    32             // rows per wave (ONE 32-row m-tile)
#define NWAVE    4
#define BLK_ROWS (NWAVE * WROWS)   // 128 rows per block
#define NTHREADS 256
#define CHUNK_CW 32             // codewords per chunk
#define NCHUNK   (NCB / CHUNK_CW)          // 32 chunks/stage
#define NGCH     (NSTAGE * NCHUNK)         // 256 flat chunks
#define CHUNK_BYTES (CHUNK_CW * 512)       // 16384

// d_ws layout
#define WS_B_BYTES     (NSTAGE * NCB * 512)            // bf16 codebook, B-frag layout, 4 MiB
#define WS_CNORM_OFF   WS_B_BYTES
#define WS_CNORM_BYTES (NSTAGE * NCB * 4)
#define WS_MSE_OFF     (WS_CNORM_OFF + WS_CNORM_BYTES)
#define WS_IDX_OFF     (WS_MSE_OFF + 64)               // u16[NSTAGE][T_ROWS], 2 MiB

typedef __attribute__((ext_vector_type(8)))  short  s16x8;
typedef __attribute__((ext_vector_type(8)))  __bf16 bf16x8;
typedef __attribute__((ext_vector_type(4)))  float  f32x4;
typedef __attribute__((ext_vector_type(16))) float  f32x16;

__device__ __forceinline__ unsigned short f2bf(float f) {
  union { float f; unsigned u; } v; v.f = f;
  unsigned r = v.u + 0x7FFFu + ((v.u >> 16) & 1u);   // RNE
  return (unsigned short)(r >> 16);
}

// ---------------------------------------------------------------------------
// Preprocess. Phase 1: fp32 CB -> bf16 B-frag copy, WRITE-coalesced.
//   block b (0..1023): group g = b>>2 (32 codewords), s-quarter s0 = (b&3)*4.
//   thread: c32 = tid&31, sh = tid>>5 -> s = s0 + (sh>>1), hi = sh&1.
//   dst = wsb + g*16384 + s*1024 + hi*512 + c32*16  (block span = contiguous
//   4KB, tid-ordered -> fully coalesced stores; reads are the transpose).
// Phase 2: cnorm with coalesced reads + 32-thread shfl reduction.
// ---------------------------------------------------------------------------
__global__ void vq_prep(const float* __restrict__ CB, char* __restrict__ wsb,
                        float* __restrict__ cnorm) {
  const int tid = threadIdx.x;
  const int b   = blockIdx.x;
  // ---- phase 1: B-frag copy ----
  {
    const int g   = b >> 2;
    const int s0  = (b & 3) * 4;
    const int c32 = tid & 31;
    const int sh  = tid >> 5;
    const int s   = s0 + (sh >> 1);
    const int hi  = sh & 1;
    const int cw  = g * 32 + c32;          // global codeword (stage built in)
    const float* src = CB + (size_t)cw * DIM + 16 * s + 8 * hi;
    f32x4 a = *(const f32x4*)(src);
    f32x4 c = *(const f32x4*)(src + 4);
    s16x8 h;
#pragma unroll
    for (int e = 0; e < 4; ++e) { h[e] = (short)f2bf(a[e]); h[4 + e] = (short)f2bf(c[e]); }
    *(s16x8*)(wsb + (size_t)g * 16384 + s * 1024 + hi * 512 + c32 * 16) = h;
  }
  // ---- phase 2: cnorm ----
  {
    const int cwl = tid >> 5;
    const int j   = tid & 31;
    const int cw  = b * 8 + cwl;
    const float* src = CB + (size_t)cw * DIM + 8 * j;
    f32x4 a = *(const f32x4*)(src);
    f32x4 c = *(const f32x4*)(src + 4);
    float sq = a[0]*a[0] + a[1]*a[1] + a[2]*a[2] + a[3]*a[3]
             + c[0]*c[0] + c[1]*c[1] + c[2]*c[2] + c[3]*c[3];
#pragma unroll
    for (int m = 1; m <= 16; m <<= 1) sq += __shfl_xor(sq, m);   // 32-thread group
    if (j == 0) cnorm[cw] = sq;
  }
}

// ---------------------------------------------------------------------------
// Search kernel. 4 waves/block; wave owns ONE 32-row m-tile; 3 blocks/CU.
// 32x32x16 MFMA layouts: A/B: lane l -> k = 8*(l>>5)+e; A row / B col = l&31.
// C/D: col = l&31, row = (reg&3) + 8*(reg>>2) + 4*(l>>5).
// acc starts at 0; -||c||^2/2 subtracted at pack so argmin dist ==
// argmax (r.c - cn/2); codeword index packed into low 10 mantissa bits ->
// fmax-only running argmax.
// ---------------------------------------------------------------------------
__global__ __launch_bounds__(NTHREADS, 3)
void vq_search(const float* __restrict__ X,
               const char* __restrict__ wsb, const float* __restrict__ cnorm,
               unsigned short* __restrict__ IDX, float* __restrict__ wsmse) {
  __shared__ __align__(16) char  lds_cb[3][CHUNK_BYTES];  // 48 KiB ring
  __shared__ unsigned short lds_idx[BLK_ROWS];            // 256 B
  __shared__ float lds_n[BLK_ROWS];                       // 512 B
  __shared__ float lds_msum[NWAVE];                       // 16 B

  const int tid  = threadIdx.x;
  const int wave = tid >> 6;           // 0..3
  const int lane = tid & 63;
  const int c32  = lane & 31;          // A row / B,D col within 32-tile
  const int hi   = lane >> 5;          // k-half (A,B) / row-offset (D)

  const int rowbase = blockIdx.x * BLK_ROWS + wave * WROWS;

  // ---- initial approximate residual = bf16(x), A-fragment layout ----
  // lane holds row rowbase + c32; step s covers dims d = 16*s + 8*hi + e
  bf16x8 af[16];
  {
    const float* px = X + (size_t)(rowbase + c32) * DIM + 8 * hi;
    float s2 = 0.f;
#pragma unroll
    for (int s = 0; s < 16; ++s) {
      f32x4 a = *(const f32x4*)(px + 16 * s);
      f32x4 b = *(const f32x4*)(px + 16 * s + 4);
      bf16x8 tt;
#pragma unroll
      for (int e = 0; e < 4; ++e) {
        tt[e] = (__bf16)a[e]; tt[4 + e] = (__bf16)b[e];
        s2 += a[e] * a[e] + b[e] * b[e];
      }
      af[s] = tt;
    }
    // n0 = ||x||^2: lane's partial covers its k-half; pair with lane^32.
    float v = s2 + __shfl_xor(s2, 32);
    if (lane < 32) lds_n[wave * WROWS + c32] = v;
  }

  // ---- prologue: stage flat chunks 0,1 into ring slots 0,1 ----
#pragma unroll
  for (int g = 0; g < 2; ++g)
#pragma unroll
    for (int i = 0; i < 4; ++i) {
      const int seg = (wave * 4 + i) * 1024;
      __builtin_amdgcn_global_load_lds(
          (const __attribute__((address_space(1))) char*)(wsb + (size_t)g * CHUNK_BYTES + seg + lane * 16),
          (__attribute__((address_space(3))) char*)(&lds_cb[g][0] + seg),
          16, 0, 0);
    }

#pragma unroll 1
  for (int st = 0; st < NSTAGE; ++st) {
    float mv[16];
#pragma unroll
    for (int r = 0; r < 16; ++r) mv[r] = -3.402823466e38f;

#pragma unroll 1
    for (int ch = 0; ch < NCHUNK; ++ch) {
      const int gf = st * NCHUNK + ch;           // flat chunk 0..255

      // top-of-chunk: everything except the last-issued prefetch (4 loads)
      // must be complete -> current chunk staged. (Compiler's cn-wait at the
      // previous pack already enforced this; kept as an explicit guarantee.)
      if (gf < NGCH - 2) {
        asm volatile("s_waitcnt vmcnt(4)" ::: "memory");
      } else {
        asm volatile("s_waitcnt vmcnt(0)" ::: "memory");
      }
      __builtin_amdgcn_sched_barrier(0);
      __builtin_amdgcn_s_barrier();              // single barrier per chunk
      __builtin_amdgcn_sched_barrier(0);

      // cn: coalesced 128B global read, consumed only at pack time
      const float cnv = cnorm[gf * CHUNK_CW + c32];

      f32x16 acc;
#pragma unroll
      for (int r = 0; r < 16; ++r) acc[r] = 0.f;

      const char* buf = &lds_cb[gf % 3][0] + lane * 16;
      __builtin_amdgcn_s_setprio(1);
#pragma unroll
      for (int s = 0; s < 16; ++s) {
        bf16x8 b = *(const bf16x8*)(buf + s * 1024);   // linear, conflict-free
        acc = __builtin_amdgcn_mfma_f32_32x32x16_bf16(af[s], b, acc, 0, 0, 0);
      }
      __builtin_amdgcn_s_setprio(0);

      // bottom-issue prefetch for flat chunk gf+2 into slot (gf+2)%3.
      // Safety: that slot held chunk gf-1; every wave's reads of gf-1
      // preceded its barrier(gf), which all waves passed before issuing here.
      // The stream is linear across stage boundaries (flat B-frag layout).
      {
        const int gt = gf + 2;
        if (gt < NGCH) {
          const char* src = wsb + (size_t)gt * CHUNK_BYTES;
          char* dst = &lds_cb[gt % 3][0];
#pragma unroll
          for (int i = 0; i < 4; ++i) {
            const int seg = (wave * 4 + i) * 1024;
            __builtin_amdgcn_global_load_lds(
                (const __attribute__((address_space(1))) char*)(src + seg + lane * 16),
                (__attribute__((address_space(3))) char*)(dst + seg),
                16, 0, 0);
          }
        }
      }

      // pack: p = (r.c - cn/2) with codeword index in low 10 mantissa bits
      const float cnh = 0.5f * cnv;
      const unsigned col = (unsigned)(ch * CHUNK_CW + c32);
#pragma unroll
      for (int r = 0; r < 16; ++r) {
        union { float f; unsigned u; } p;
        p.f = acc[r] - cnh;
        p.u = (p.u & 0xFFFFFC00u) | col;
        mv[r] = fmaxf(mv[r], p.f);
      }
    }

    // ---- cross-lane argmax + ||r||^2 recursion ----
    // r: row = (r&3) + 8*(r>>2) + 4*hi ; reduce over the 32 cols
    float msum = 0.f;
#pragma unroll
    for (int r = 0; r < 16; ++r) {
      float v = mv[r];
#pragma unroll
      for (int m = 1; m <= 16; m <<= 1) v = fmaxf(v, __shfl_xor(v, m));
      union { float f; unsigned u; } w; w.f = v;
      const float vtrue = __builtin_bit_cast(float, w.u & 0xFFFFFC00u);
      const int   row   = (r & 3) + 8 * (r >> 2) + 4 * hi;
      const int   wrow  = wave * WROWS + row;
      const float n_new = lds_n[wrow] - 2.0f * vtrue;   // min-dist identity
      msum += n_new;
      if (c32 == 0) {
        lds_n[wrow]   = n_new;
        const int ix = (int)(w.u & 1023u);
        lds_idx[wrow] = (unsigned short)ix;
        IDX[st * T_ROWS + rowbase + row] = (unsigned short)ix;
      }
    }
    // msum uniform within each 32-lane half; halves cover disjoint rows
    msum += __shfl_xor(msum, 32);
    if (lane == 0) lds_msum[wave] = msum;

    if (st != NSTAGE - 1) {
      // ---- approximate af update (ranking only) from the B-layout copy:
      //      dims d=16s+8hi+e of codeword idx live at
      //      wsb + st*512K + (idx>>5)*16384 + s*1024 + hi*512 + (idx&31)*16
      const int idx = (int)lds_idx[wave * WROWS + c32];
      const char* q = wsb + (size_t)st * NCB * 512
                    + (size_t)(idx >> 5) * 16384 + hi * 512 + (idx & 31) * 16;
#pragma unroll
      for (int s = 0; s < 16; ++s) {
        bf16x8 qb = *(const bf16x8*)(q + s * 1024);
        bf16x8 tt = af[s];
#pragma unroll
        for (int e = 0; e < 8; ++e)
          tt[e] = (__bf16)((float)tt[e] - (float)qb[e]);
        af[s] = tt;
      }
    }

    // stage-end barrier: orders lds_msum before the block reduce (also
    // absorbs the af-update drift before the next chunk's top barrier).
    __builtin_amdgcn_s_barrier();

    // block-level MSE reduction: 1 atomic per block per stage
    if (wave == 0) {
      float v = (lane < NWAVE) ? lds_msum[lane] : 0.f;
      v += __shfl_xor(v, 1);
      v += __shfl_xor(v, 2);
      if (lane == 0) atomicAdd(wsmse + st, v);
    }
  }
}

// ---------------------------------------------------------------------------
// Recon kernel: OUT[row] = sum of the 8 chosen bf16 codewords, read from the
// B-layout copy. 8 threads/row; thread g covers dims g*32..g*32+31:
//   dim d = g*32 + k*8  ->  s = 2g + (k>>1), hi = k&1
// ---------------------------------------------------------------------------
__global__ __launch_bounds__(256)
void vq_recon(const char* __restrict__ wsb, const unsigned short* __restrict__ IDX,
              float* __restrict__ OUT) {
  const int tid = threadIdx.x;
  const int row = blockIdx.x * (256 / 8) + (tid >> 3);
  const int g   = tid & 7;             // dims g*32 .. g*32+31

  int idxs[NSTAGE];
#pragma unroll
  for (int st = 0; st < NSTAGE; ++st) idxs[st] = IDX[st * T_ROWS + row];

  float a[32];
#pragma unroll
  for (int d = 0; d < 32; ++d) a[d] = 0.f;

#pragma unroll
  for (int st = 0; st < NSTAGE; ++st) {
    const char* q = wsb + (size_t)st * NCB * 512
                  + (size_t)(idxs[st] >> 5) * 16384 + (idxs[st] & 31) * 16;
#pragma unroll
    for (int k = 0; k < 4; ++k) {
      const int s  = 2 * g + (k >> 1);
      const int h2 = (k & 1);
      bf16x8 qb = *(const bf16x8*)(q + s * 1024 + h2 * 512);
#pragma unroll
      for (int e = 0; e < 8; ++e) a[k * 8 + e] += (float)qb[e];
    }
  }

  float* po = OUT + (size_t)row * DIM + g * 32;
#pragma unroll
  for (int m = 0; m < 8; ++m) {
    f32x4 o = {a[4 * m], a[4 * m + 1], a[4 * m + 2], a[4 * m + 3]};
    *(f32x4*)(po + 4 * m) = o;
  }
}

__global__ void vq_fin(const float* __restrict__ wsmse, float* __restrict__ OUT) {
  const int i = threadIdx.x;
  if (i < NSTAGE) {
    OUT[(size_t)T_ROWS * DIM + i] = wsmse[i] * (1.0f / ((float)T_ROWS * (float)DIM));
  }
}

extern "C" void kernel_launch(void* const* d_in, const int* in_sizes, int n_in,
                              void* d_out, int out_size, void* d_ws, size_t ws_size,
                              hipStream_t stream) {
  (void)in_sizes; (void)n_in; (void)out_size; (void)ws_size;
  const float* X  = (const float*)d_in[0];
  const float* CB = (const float*)d_in[1];
  float* OUT = (float*)d_out;
  char*  wsb   = (char*)d_ws;
  float* cnorm = (float*)((char*)d_ws + WS_CNORM_OFF);
  float* wsmse = (float*)((char*)d_ws + WS_MSE_OFF);
  unsigned short* IDX = (unsigned short*)((char*)d_ws + WS_IDX_OFF);

  hipMemsetAsync(wsmse, 0, NSTAGE * sizeof(float), stream);
  hipLaunchKernelGGL(vq_prep, dim3(1024), dim3(256), 0, stream,
                     CB, wsb, cnorm);
  hipLaunchKernelGGL(vq_search, dim3(T_ROWS / BLK_ROWS), dim3(NTHREADS), 0, stream,
                     X, wsb, cnorm, IDX, wsmse);
  hipLaunchKernelGGL(vq_recon, dim3(T_ROWS / (256 / 8)), dim3(256), 0, stream,
                     wsb, IDX, OUT);
  hipLaunchKernelGGL(vq_fin, dim3(1), dim3(64), 0, stream, wsmse, OUT);
}